// Round 4
// baseline (138.494 us; speedup 1.0000x reference)
//
#include <hip/hip_runtime.h>

// Problem constants (fixed by setup_inputs): image (4,3,1024,1024) f32,
// pMtrx (4,2,3) f32, W=H=1024, align_corners=True.
//
// Forward-pass collapse: g0 = stop_gradient(grid) => grid - g0 == 0 exactly,
// so out = transpose(bilinear_sample(image, affine_grid(pMtrx,...)), (0,3,1,2)).
// The NUM_AUX noisy samples / 2x2 solves contribute exactly 0 to the output.
//
// R4: latency-bound fix. R3 had VGPR=32 -> compiler serialized loads (MLP~6).
// Phase-separated structure: all 16 tap offsets+weights first, then 48
// independent scalar loads into a live array (forces high VGPR / high MLP),
// then FMA reduction + float4 nontemporal stores.

#define B_  4
#define C_  3
#define HI  1024
#define WI  1024
#define HO  1024
#define WO  1024

typedef float vf4 __attribute__((ext_vector_type(4)));

__global__ __launch_bounds__(256) void warp_bilinear4_kernel(
    const float* __restrict__ image,   // (B, C, HI, WI)
    const float* __restrict__ theta,   // (B, 2, 3)
    float* __restrict__ out)           // (B, C, HO, WO)
{
    // One block = one output row (256 threads x 4 px = 1024 = WO).
    const int h = blockIdx.x & (HO - 1);
    const int b = blockIdx.x >> 10;
    const int w0 = threadIdx.x << 2;

    const float* t = theta + b * 6;    // uniform -> s_loads
    const float t0 = t[0], t1 = t[1], t2 = t[2];
    const float t3 = t[3], t4 = t[4], t5 = t[5];

    const float ys = -1.0f + 2.0f * (float)h / (float)(HO - 1);
    const float cy = t1 * ys + t2;   // x = t0*xs + cy
    const float dy = t4 * ys + t5;   // y = t3*xs + dy

    const float* imgb = image + (size_t)b * (C_ * HI * WI);

    // ---- Phase 1: addresses + validity-folded weights for 4 px ----
    int   off[4][4];   // [px][tap: 00,10,01,11]
    float wt [4][4];

#pragma unroll
    for (int px = 0; px < 4; ++px) {
        const int w = w0 + px;
        const float xs = -1.0f + 2.0f * (float)w / (float)(WO - 1);
        const float x = t0 * xs + cy;
        const float y = t3 * xs + dy;

        const float ix = (x + 1.0f) * 0.5f * (float)(WI - 1);
        const float iy = (y + 1.0f) * 0.5f * (float)(HI - 1);

        const float x0f = floorf(ix);
        const float y0f = floorf(iy);
        const float wx1 = ix - x0f;
        const float wy1 = iy - y0f;

        const int x0 = (int)x0f;
        const int y0 = (int)y0f;

        const float ax0 = (1.0f - wx1) * ((x0 >= 0 && x0 <= WI - 1) ? 1.0f : 0.0f);
        const float ax1 = wx1          * ((x0 >= -1 && x0 <= WI - 2) ? 1.0f : 0.0f);
        const float ay0 = (1.0f - wy1) * ((y0 >= 0 && y0 <= HI - 1) ? 1.0f : 0.0f);
        const float ay1 = wy1          * ((y0 >= -1 && y0 <= HI - 2) ? 1.0f : 0.0f);

        const int xc0 = min(max(x0, 0), WI - 1);
        const int xc1 = min(max(x0 + 1, 0), WI - 1);
        const int yc0 = min(max(y0, 0), HI - 1);
        const int yc1 = min(max(y0 + 1, 0), HI - 1);

        off[px][0] = yc0 * WI + xc0;
        off[px][1] = yc0 * WI + xc1;
        off[px][2] = yc1 * WI + xc0;
        off[px][3] = yc1 * WI + xc1;
        wt [px][0] = ax0 * ay0;
        wt [px][1] = ax1 * ay0;
        wt [px][2] = ax0 * ay1;
        wt [px][3] = ax1 * ay1;
    }

    // ---- Phase 2: 48 independent loads, all live simultaneously ----
    float v[C_][16];
#pragma unroll
    for (int c = 0; c < C_; ++c) {
        const float* p = imgb + c * (HI * WI);
#pragma unroll
        for (int px = 0; px < 4; ++px) {
#pragma unroll
            for (int tap = 0; tap < 4; ++tap) {
                v[c][px * 4 + tap] = p[off[px][tap]];
            }
        }
    }

    // ---- Phase 3: reduce + store ----
    float* ob = out + (size_t)b * (C_ * HO * WO) + h * WO + w0;
#pragma unroll
    for (int c = 0; c < C_; ++c) {
        vf4 r;
#pragma unroll
        for (int px = 0; px < 4; ++px) {
            r[px] = v[c][px * 4 + 0] * wt[px][0]
                  + v[c][px * 4 + 1] * wt[px][1]
                  + v[c][px * 4 + 2] * wt[px][2]
                  + v[c][px * 4 + 3] * wt[px][3];
        }
        __builtin_nontemporal_store(r, (vf4*)(ob + c * (HO * WO)));
    }
}

extern "C" void kernel_launch(void* const* d_in, const int* in_sizes, int n_in,
                              void* d_out, int out_size, void* d_ws, size_t ws_size,
                              hipStream_t stream) {
    const float* image = (const float*)d_in[0];
    const float* theta = (const float*)d_in[1];
    float* out = (float*)d_out;

    const int grid = B_ * HO;   // one block per output row = 4096 blocks
    warp_bilinear4_kernel<<<grid, 256, 0, stream>>>(image, theta, out);
}

// Round 5
// 117.726 us; speedup vs baseline: 1.1764x; 1.1764x over previous
//
#include <hip/hip_runtime.h>

// Problem constants (fixed by setup_inputs): image (4,3,1024,1024) f32,
// pMtrx (4,2,3) f32, W=H=1024, align_corners=True.
//
// Forward-pass collapse: g0 = stop_gradient(grid) => grid - g0 == 0 exactly,
// so out = transpose(bilinear_sample(image, affine_grid(pMtrx,...)), (0,3,1,2)).
//
// R5: LDS band tiling. R1/R3/R4 plateaued at ~43-58us because per-lane
// scalar gathers cross a ~13-row diagonal staircase (t3~0.05) -> scattered
// 4B VMEM at ~3 TB/s effective. Now: each block = 32x16 output tile; stage
// the affine-preimage band (52x32 floats x 3ch = 19.9 KB LDS) with aligned
// coalesced float4 loads, taps read LDS (consecutive-lane x -> conflict-free).
// Band box from the 4 tile corners (affine extremes are at corners), -1/-3
// slack for alignment+ulp; LDS indices clamped as a correctness backstop.

#define B_  4
#define C_  3
#define HI  1024
#define WI  1024
#define HO  1024
#define WO  1024

#define TW  32        // tile width (px)
#define TH  16        // tile height (px)
#define BANDW 52      // band width in floats (row stride, %4==0)
#define BANDH 32      // band height in rows
#define NSEG (BANDW/4)            // 13 float4 segments per row
#define LDS_CH (BANDH * BANDW)    // floats per channel

typedef float vf4 __attribute__((ext_vector_type(4)));

__device__ __forceinline__ float2 map_px(int w, int h,
                                         float t0, float t1, float t2,
                                         float t3, float t4, float t5) {
    const float xs = -1.0f + 2.0f * (float)w / (float)(WO - 1);
    const float ys = -1.0f + 2.0f * (float)h / (float)(HO - 1);
    const float x = t0 * xs + (t1 * ys + t2);
    const float y = t3 * xs + (t4 * ys + t5);
    const float ix = (x + 1.0f) * 0.5f * (float)(WI - 1);
    const float iy = (y + 1.0f) * 0.5f * (float)(HI - 1);
    return make_float2(ix, iy);
}

__global__ __launch_bounds__(256) void warp_bilinear_tile_kernel(
    const float* __restrict__ image,   // (B, C, HI, WI)
    const float* __restrict__ theta,   // (B, 2, 3)
    float* __restrict__ out)           // (B, C, HO, WO)
{
    __shared__ float lds[C_ * LDS_CH];   // 4992 floats = 19968 B

    const int bid = blockIdx.x;
    const int b   = bid >> 11;           // 2048 tiles per batch image
    const int rem = bid & 2047;
    const int h0  = (rem >> 5) * TH;     // 64 tile rows
    const int w0  = (rem & 31) * TW;     // 32 tile cols

    const float* t = theta + b * 6;
    const float t0 = t[0], t1 = t[1], t2 = t[2];
    const float t3 = t[3], t4 = t[4], t5 = t[5];

    // ---- band bounding box from the 4 tile corners (block-uniform) ----
    const float2 c00 = map_px(w0,        h0,        t0,t1,t2,t3,t4,t5);
    const float2 c10 = map_px(w0+TW-1,   h0,        t0,t1,t2,t3,t4,t5);
    const float2 c01 = map_px(w0,        h0+TH-1,   t0,t1,t2,t3,t4,t5);
    const float2 c11 = map_px(w0+TW-1,   h0+TH-1,   t0,t1,t2,t3,t4,t5);

    const float ixmin = fminf(fminf(c00.x, c10.x), fminf(c01.x, c11.x));
    const float iymin = fminf(fminf(c00.y, c10.y), fminf(c01.y, c11.y));

    int bx = (int)floorf(ixmin) - 1;
    bx = min(max(bx, 0), WI - BANDW);
    bx &= ~3;                            // 16B-align row base (972 %4==0)
    int by = (int)floorf(iymin) - 1;
    by = min(max(by, 0), HI - BANDH);

    const float* imgb = image + (size_t)b * (C_ * HI * WI);

    // ---- stage band: C*BANDH*NSEG float4 segs, coalesced + aligned ----
#pragma unroll 2
    for (int i = threadIdx.x; i < C_ * BANDH * NSEG; i += 256) {
        const int c   = i / (BANDH * NSEG);
        const int rr  = i - c * (BANDH * NSEG);
        const int r   = rr / NSEG;
        const int seg = rr - r * NSEG;
        const vf4 v = *(const vf4*)(imgb + c * (HI * WI) + (by + r) * WI + bx + seg * 4);
        *(vf4*)(lds + c * LDS_CH + r * BANDW + seg * 4) = v;
    }
    __syncthreads();

    // ---- compute: 2 px per thread (rows ty and ty+8 of the tile) ----
    const int wloc = threadIdx.x & 31;
    const int ty   = threadIdx.x >> 5;
    const int w    = w0 + wloc;

    float* ob = out + (size_t)b * (C_ * HO * WO) + w;

#pragma unroll
    for (int k = 0; k < 2; ++k) {
        const int h = h0 + ty + 8 * k;

        const float2 ixy = map_px(w, h, t0, t1, t2, t3, t4, t5);
        const float ix = ixy.x, iy = ixy.y;

        const float x0f = floorf(ix);
        const float y0f = floorf(iy);
        const float wx1 = ix - x0f;
        const float wy1 = iy - y0f;
        const int x0 = (int)x0f;
        const int y0 = (int)y0f;

        // validity-folded axis weights (identical to R3 semantics)
        const float ax0 = (1.0f - wx1) * ((x0 >= 0 && x0 <= WI - 1) ? 1.0f : 0.0f);
        const float ax1 = wx1          * ((x0 >= -1 && x0 <= WI - 2) ? 1.0f : 0.0f);
        const float ay0 = (1.0f - wy1) * ((y0 >= 0 && y0 <= HI - 1) ? 1.0f : 0.0f);
        const float ay1 = wy1          * ((y0 >= -1 && y0 <= HI - 2) ? 1.0f : 0.0f);

        const float w00 = ax0 * ay0, w10 = ax1 * ay0;
        const float w01 = ax0 * ay1, w11 = ax1 * ay1;

        // clamped global taps -> band-local indices (clamped backstop)
        const int xl0 = min(max(min(max(x0,     0), WI - 1) - bx, 0), BANDW - 1);
        const int xl1 = min(max(min(max(x0 + 1, 0), WI - 1) - bx, 0), BANDW - 1);
        const int yl0 = min(max(min(max(y0,     0), HI - 1) - by, 0), BANDH - 1);
        const int yl1 = min(max(min(max(y0 + 1, 0), HI - 1) - by, 0), BANDH - 1);

        const int o00 = yl0 * BANDW + xl0;
        const int o10 = yl0 * BANDW + xl1;
        const int o01 = yl1 * BANDW + xl0;
        const int o11 = yl1 * BANDW + xl1;

#pragma unroll
        for (int c = 0; c < C_; ++c) {
            const float* p = lds + c * LDS_CH;
            const float v = p[o00] * w00 + p[o10] * w10
                          + p[o01] * w01 + p[o11] * w11;
            __builtin_nontemporal_store(v, ob + c * (HO * WO) + h * WO);
        }
    }
}

extern "C" void kernel_launch(void* const* d_in, const int* in_sizes, int n_in,
                              void* d_out, int out_size, void* d_ws, size_t ws_size,
                              hipStream_t stream) {
    const float* image = (const float*)d_in[0];
    const float* theta = (const float*)d_in[1];
    float* out = (float*)d_out;

    const int grid = B_ * (HO / TH) * (WO / TW);   // 4*64*32 = 8192 blocks
    warp_bilinear_tile_kernel<<<grid, 256, 0, stream>>>(image, theta, out);
}

// Round 6
// 114.963 us; speedup vs baseline: 1.2047x; 1.0240x over previous
//
#include <hip/hip_runtime.h>

// Problem constants (fixed by setup_inputs): image (4,3,1024,1024) f32,
// pMtrx (4,2,3) f32, W=H=1024, align_corners=True.
//
// Forward-pass collapse: g0 = stop_gradient(grid) => grid - g0 == 0 exactly,
// so out = transpose(bilinear_sample(image, affine_grid(pMtrx,...)), (0,3,1,2)).
//
// R6: async staging. R5 (~38us) paid for staging twice: global->VGPR->ds_write
// (163MB through VMEM return path + LDS write pipe). Now:
//  - __builtin_amdgcn_global_load_lds width=16: DMA direct to LDS, zero
//    ds_write instructions (the m93->m97 lever). LDS dest is wave-uniform
//    base + lane*16, so the band is packed raster [c][row][seg], stride 52.
//  - square 32x32 tile: staged-overlap 3.25x -> 2.44x, 2x arithmetic per
//    staged byte (amortizes the stage->sync bubble).
// Compute mapping keeps consecutive-lane x (2 lanes/bank -> conflict-free).

#define B_  4
#define C_  3
#define HI  1024
#define WI  1024
#define HO  1024
#define WO  1024

#define TW  32
#define TH  32
#define BANDW 52                      // floats per band row (13 x float4)
#define BANDH 48
#define NSEG  13                      // BANDW/4
#define SEGS_CH (BANDH * NSEG)        // 624 float4-segments per channel
#define SEGS_TOT (C_ * SEGS_CH)       // 1872
#define LDS_CH (BANDH * BANDW)        // 2496 floats per channel
#define NITER ((SEGS_TOT + 63) / 64)  // 30 wave-wide DMA instructions

typedef __attribute__((address_space(3))) void* lds_vp;
typedef const __attribute__((address_space(1))) void* gbl_vp;

__device__ __forceinline__ float2 map_px(int w, int h,
                                         float t0, float t1, float t2,
                                         float t3, float t4, float t5) {
    const float xs = -1.0f + 2.0f * (float)w / (float)(WO - 1);
    const float ys = -1.0f + 2.0f * (float)h / (float)(HO - 1);
    const float x = t0 * xs + (t1 * ys + t2);
    const float y = t3 * xs + (t4 * ys + t5);
    const float ix = (x + 1.0f) * 0.5f * (float)(WI - 1);
    const float iy = (y + 1.0f) * 0.5f * (float)(HI - 1);
    return make_float2(ix, iy);
}

__global__ __launch_bounds__(256) void warp_bilinear_dma_kernel(
    const float* __restrict__ image,   // (B, C, HI, WI)
    const float* __restrict__ theta,   // (B, 2, 3)
    float* __restrict__ out)           // (B, C, HO, WO)
{
    __shared__ float lds[NITER * 256];   // 7680 floats = 30720 B (tail pad)

    const int bid = blockIdx.x;
    const int b   = bid >> 10;           // 1024 tiles per batch image
    const int rem = bid & 1023;
    const int h0  = (rem >> 5) * TH;     // 32 tile rows
    const int w0  = (rem & 31) * TW;     // 32 tile cols

    const float* t = theta + b * 6;
    const float t0 = t[0], t1 = t[1], t2 = t[2];
    const float t3 = t[3], t4 = t[4], t5 = t[5];

    // ---- band bounding box from the 4 tile corners (block-uniform) ----
    const float2 c00 = map_px(w0,        h0,        t0,t1,t2,t3,t4,t5);
    const float2 c10 = map_px(w0+TW-1,   h0,        t0,t1,t2,t3,t4,t5);
    const float2 c01 = map_px(w0,        h0+TH-1,   t0,t1,t2,t3,t4,t5);
    const float2 c11 = map_px(w0+TW-1,   h0+TH-1,   t0,t1,t2,t3,t4,t5);

    const float ixmin = fminf(fminf(c00.x, c10.x), fminf(c01.x, c11.x));
    const float iymin = fminf(fminf(c00.y, c10.y), fminf(c01.y, c11.y));

    int bx = (int)floorf(ixmin) - 1;
    bx = min(max(bx, 0), WI - BANDW);
    bx &= ~3;                            // 16B-align row base
    int by = (int)floorf(iymin) - 1;
    by = min(max(by, 0), HI - BANDH);

    const float* imgb = image + (size_t)b * (C_ * HI * WI);

    // ---- stage band via global_load_lds width=16 (no VGPR roundtrip) ----
    // LDS is packed in seg order: float offset of seg = seg*4
    //   = c*LDS_CH + r*BANDW + s*4  (LDS_CH = 48*52, BANDW = 52).
    const int wv   = threadIdx.x >> 6;   // wave id 0..3
    const int lane = threadIdx.x & 63;
#pragma unroll
    for (int j = wv; j < NITER; j += 4) {
        const int seg = j * 64 + lane;
        if (seg < SEGS_TOT) {
            const int c  = seg / SEGS_CH;
            const int r2 = seg - c * SEGS_CH;
            const int r  = r2 / NSEG;
            const int s  = r2 - r * NSEG;
            const float* gp = imgb + c * (HI * WI) + (by + r) * WI + (bx + s * 4);
            __builtin_amdgcn_global_load_lds((gbl_vp)gp, (lds_vp)(lds + j * 256),
                                             16, 0, 0);
        }
    }
    __syncthreads();   // drains vmcnt before barrier (single-stage: fine)

    // ---- compute: 4 rows per thread, consecutive-lane x (bank-free) ----
    const int wloc = threadIdx.x & 31;
    const int tyq  = threadIdx.x >> 5;   // 0..7
    const int w    = w0 + wloc;

    float* ob = out + (size_t)b * (C_ * HO * WO) + w;

#pragma unroll
    for (int k = 0; k < 4; ++k) {
        const int h = h0 + tyq + 8 * k;

        const float2 ixy = map_px(w, h, t0, t1, t2, t3, t4, t5);
        const float ix = ixy.x, iy = ixy.y;

        const float x0f = floorf(ix);
        const float y0f = floorf(iy);
        const float wx1 = ix - x0f;
        const float wy1 = iy - y0f;
        const int x0 = (int)x0f;
        const int y0 = (int)y0f;

        // validity-folded axis weights (same semantics as R1/R3/R5)
        const float ax0 = (1.0f - wx1) * ((x0 >= 0 && x0 <= WI - 1) ? 1.0f : 0.0f);
        const float ax1 = wx1          * ((x0 >= -1 && x0 <= WI - 2) ? 1.0f : 0.0f);
        const float ay0 = (1.0f - wy1) * ((y0 >= 0 && y0 <= HI - 1) ? 1.0f : 0.0f);
        const float ay1 = wy1          * ((y0 >= -1 && y0 <= HI - 2) ? 1.0f : 0.0f);

        const float w00 = ax0 * ay0, w10 = ax1 * ay0;
        const float w01 = ax0 * ay1, w11 = ax1 * ay1;

        // clamped global taps -> band-local indices (clamped backstop)
        const int xl0 = min(max(min(max(x0,     0), WI - 1) - bx, 0), BANDW - 1);
        const int xl1 = min(max(min(max(x0 + 1, 0), WI - 1) - bx, 0), BANDW - 1);
        const int yl0 = min(max(min(max(y0,     0), HI - 1) - by, 0), BANDH - 1);
        const int yl1 = min(max(min(max(y0 + 1, 0), HI - 1) - by, 0), BANDH - 1);

        const int o00 = yl0 * BANDW + xl0;
        const int o10 = yl0 * BANDW + xl1;
        const int o01 = yl1 * BANDW + xl0;
        const int o11 = yl1 * BANDW + xl1;

#pragma unroll
        for (int c = 0; c < C_; ++c) {
            const float* p = lds + c * LDS_CH;
            const float v = p[o00] * w00 + p[o10] * w10
                          + p[o01] * w01 + p[o11] * w11;
            __builtin_nontemporal_store(v, ob + c * (HO * WO) + h * WO);
        }
    }
}

extern "C" void kernel_launch(void* const* d_in, const int* in_sizes, int n_in,
                              void* d_out, int out_size, void* d_ws, size_t ws_size,
                              hipStream_t stream) {
    const float* image = (const float*)d_in[0];
    const float* theta = (const float*)d_in[1];
    float* out = (float*)d_out;

    const int grid = B_ * (HO / TH) * (WO / TW);   // 4*32*32 = 4096 blocks
    warp_bilinear_dma_kernel<<<grid, 256, 0, stream>>>(image, theta, out);
}

// Round 7
// 113.103 us; speedup vs baseline: 1.2245x; 1.0164x over previous
//
#include <hip/hip_runtime.h>

// Problem constants (fixed by setup_inputs): image (4,3,1024,1024) f32,
// pMtrx (4,2,3) f32, W=H=1024, align_corners=True.
//
// Forward-pass collapse: g0 = stop_gradient(grid) => grid - g0 == 0 exactly,
// so out = transpose(bilinear_sample(image, affine_grid(pMtrx,...)), (0,3,1,2)).
//
// R7: block-uniform interior fast path. R6 (~35us est) was issue-bound:
// ~28 of ~50 VALU ops/px were validity masks + clamp backstops, and 12
// scalar ds_read_b32/px. The tile corner bbox exactly bounds all taps
// (affine extremes at corners): if 1<=ix<=WI-2 and 1<=iy<=HI-2 over the
// tile, skip all masks/clamps and read taps as base[0],[1],[52],[53]
// (-> ds_read2_b32 pairs). Edge tiles (~10%) keep the full-clamp path.
// Staging unchanged: global_load_lds width=16 DMA, 32x32 tile, 52x48 band.

#define B_  4
#define C_  3
#define HI  1024
#define WI  1024
#define HO  1024
#define WO  1024

#define TW  32
#define TH  32
#define BANDW 52                      // floats per band row (13 x float4)
#define BANDH 48
#define NSEG  13                      // BANDW/4
#define SEGS_CH (BANDH * NSEG)        // 624 float4-segments per channel
#define SEGS_TOT (C_ * SEGS_CH)       // 1872
#define LDS_CH (BANDH * BANDW)        // 2496 floats per channel
#define NITER ((SEGS_TOT + 63) / 64)  // 30 wave-wide DMA instructions

typedef __attribute__((address_space(3))) void* lds_vp;
typedef const __attribute__((address_space(1))) void* gbl_vp;

__device__ __forceinline__ float2 map_px(int w, int h,
                                         float t0, float t1, float t2,
                                         float t3, float t4, float t5) {
    const float xs = -1.0f + 2.0f * (float)w / (float)(WO - 1);
    const float ys = -1.0f + 2.0f * (float)h / (float)(HO - 1);
    const float x = t0 * xs + (t1 * ys + t2);
    const float y = t3 * xs + (t4 * ys + t5);
    const float ix = (x + 1.0f) * 0.5f * (float)(WI - 1);
    const float iy = (y + 1.0f) * 0.5f * (float)(HI - 1);
    return make_float2(ix, iy);
}

__global__ __launch_bounds__(256) void warp_bilinear_fast_kernel(
    const float* __restrict__ image,   // (B, C, HI, WI)
    const float* __restrict__ theta,   // (B, 2, 3)
    float* __restrict__ out)           // (B, C, HO, WO)
{
    __shared__ float lds[NITER * 256];   // 7680 floats = 30720 B (tail pad)

    const int bid = blockIdx.x;
    const int b   = bid >> 10;           // 1024 tiles per batch image
    const int rem = bid & 1023;
    const int h0  = (rem >> 5) * TH;     // 32 tile rows
    const int w0  = (rem & 31) * TW;     // 32 tile cols

    const float* t = theta + b * 6;
    const float t0 = t[0], t1 = t[1], t2 = t[2];
    const float t3 = t[3], t4 = t[4], t5 = t[5];

    // ---- band bounding box from the 4 tile corners (block-uniform) ----
    const float2 c00 = map_px(w0,        h0,        t0,t1,t2,t3,t4,t5);
    const float2 c10 = map_px(w0+TW-1,   h0,        t0,t1,t2,t3,t4,t5);
    const float2 c01 = map_px(w0,        h0+TH-1,   t0,t1,t2,t3,t4,t5);
    const float2 c11 = map_px(w0+TW-1,   h0+TH-1,   t0,t1,t2,t3,t4,t5);

    const float ixmin = fminf(fminf(c00.x, c10.x), fminf(c01.x, c11.x));
    const float iymin = fminf(fminf(c00.y, c10.y), fminf(c01.y, c11.y));
    const float ixmax = fmaxf(fmaxf(c00.x, c10.x), fmaxf(c01.x, c11.x));
    const float iymax = fmaxf(fmaxf(c00.y, c10.y), fmaxf(c01.y, c11.y));

    int bx = (int)floorf(ixmin) - 1;
    bx = min(max(bx, 0), WI - BANDW);
    bx &= ~3;                            // 16B-align row base
    int by = (int)floorf(iymin) - 1;
    by = min(max(by, 0), HI - BANDH);

    const float* imgb = image + (size_t)b * (C_ * HI * WI);

    // ---- stage band via global_load_lds width=16 (no VGPR roundtrip) ----
    const int wv   = threadIdx.x >> 6;   // wave id 0..3
    const int lane = threadIdx.x & 63;
#pragma unroll
    for (int j = wv; j < NITER; j += 4) {
        const int seg = j * 64 + lane;
        if (seg < SEGS_TOT) {
            const int c  = seg / SEGS_CH;
            const int r2 = seg - c * SEGS_CH;
            const int r  = r2 / NSEG;
            const int s  = r2 - r * NSEG;
            const float* gp = imgb + c * (HI * WI) + (by + r) * WI + (bx + s * 4);
            __builtin_amdgcn_global_load_lds((gbl_vp)gp, (lds_vp)(lds + j * 256),
                                             16, 0, 0);
        }
    }
    __syncthreads();

    // ---- compute: 4 rows per thread, consecutive-lane x (bank-free) ----
    const int wloc = threadIdx.x & 31;
    const int tyq  = threadIdx.x >> 5;   // 0..7
    const int w    = w0 + wloc;

    float* ob = out + (size_t)b * (C_ * HO * WO) + w;

    // block-uniform interior test: every tap strictly in-bounds
    const bool interior = (ixmin >= 1.0f) && (ixmax <= (float)(WI - 2)) &&
                          (iymin >= 1.0f) && (iymax <= (float)(HI - 2));

    if (interior) {
        // -------- fast path: no masks, no clamps, ds_read2-friendly ----
#pragma unroll
        for (int k = 0; k < 4; ++k) {
            const int h = h0 + tyq + 8 * k;
            const float2 ixy = map_px(w, h, t0, t1, t2, t3, t4, t5);
            const float ix = ixy.x, iy = ixy.y;

            const float x0f = floorf(ix);
            const float y0f = floorf(iy);
            const float wx1 = ix - x0f;
            const float wy1 = iy - y0f;
            const float wx0 = 1.0f - wx1;
            const float wy0 = 1.0f - wy1;

            const float w00 = wx0 * wy0, w10 = wx1 * wy0;
            const float w01 = wx0 * wy1, w11 = wx1 * wy1;

            const int ox = (int)x0f - bx;
            const int oy = (int)y0f - by;
            const float* base0 = lds + oy * BANDW + ox;

#pragma unroll
            for (int c = 0; c < C_; ++c) {
                const float* p = base0 + c * LDS_CH;
                const float v = p[0]         * w00 + p[1]         * w10
                              + p[BANDW]     * w01 + p[BANDW + 1] * w11;
                __builtin_nontemporal_store(v, ob + c * (HO * WO) + h * WO);
            }
        }
    } else {
        // -------- edge path: full validity-folded weights + clamps ------
#pragma unroll
        for (int k = 0; k < 4; ++k) {
            const int h = h0 + tyq + 8 * k;
            const float2 ixy = map_px(w, h, t0, t1, t2, t3, t4, t5);
            const float ix = ixy.x, iy = ixy.y;

            const float x0f = floorf(ix);
            const float y0f = floorf(iy);
            const float wx1 = ix - x0f;
            const float wy1 = iy - y0f;
            const int x0 = (int)x0f;
            const int y0 = (int)y0f;

            const float ax0 = (1.0f - wx1) * ((x0 >= 0 && x0 <= WI - 1) ? 1.0f : 0.0f);
            const float ax1 = wx1          * ((x0 >= -1 && x0 <= WI - 2) ? 1.0f : 0.0f);
            const float ay0 = (1.0f - wy1) * ((y0 >= 0 && y0 <= HI - 1) ? 1.0f : 0.0f);
            const float ay1 = wy1          * ((y0 >= -1 && y0 <= HI - 2) ? 1.0f : 0.0f);

            const float w00 = ax0 * ay0, w10 = ax1 * ay0;
            const float w01 = ax0 * ay1, w11 = ax1 * ay1;

            const int xl0 = min(max(min(max(x0,     0), WI - 1) - bx, 0), BANDW - 1);
            const int xl1 = min(max(min(max(x0 + 1, 0), WI - 1) - bx, 0), BANDW - 1);
            const int yl0 = min(max(min(max(y0,     0), HI - 1) - by, 0), BANDH - 1);
            const int yl1 = min(max(min(max(y0 + 1, 0), HI - 1) - by, 0), BANDH - 1);

            const int o00 = yl0 * BANDW + xl0;
            const int o10 = yl0 * BANDW + xl1;
            const int o01 = yl1 * BANDW + xl0;
            const int o11 = yl1 * BANDW + xl1;

#pragma unroll
            for (int c = 0; c < C_; ++c) {
                const float* p = lds + c * LDS_CH;
                const float v = p[o00] * w00 + p[o10] * w10
                              + p[o01] * w01 + p[o11] * w11;
                __builtin_nontemporal_store(v, ob + c * (HO * WO) + h * WO);
            }
        }
    }
}

extern "C" void kernel_launch(void* const* d_in, const int* in_sizes, int n_in,
                              void* d_out, int out_size, void* d_ws, size_t ws_size,
                              hipStream_t stream) {
    const float* image = (const float*)d_in[0];
    const float* theta = (const float*)d_in[1];
    float* out = (float*)d_out;

    const int grid = B_ * (HO / TH) * (WO / TW);   // 4*32*32 = 4096 blocks
    warp_bilinear_fast_kernel<<<grid, 256, 0, stream>>>(image, theta, out);
}